// Round 1
// baseline (1606.012 us; speedup 1.0000x reference)
//
#include <hip/hip_runtime.h>
#include <math.h>

#define LL 2048
#define DD 128
#define BB 4

// ================= proj GEMM: C(8192x128 per arr) = x(8192x2048) @ w^T ================
__global__ __launch_bounds__(256) void proj_gemm(
    const float* __restrict__ x,
    const float* __restrict__ kw, const float* __restrict__ qw, const float* __restrict__ vw,
    const float* __restrict__ kb, const float* __restrict__ qb, const float* __restrict__ vb,
    float* __restrict__ k0, float* __restrict__ q0, float* __restrict__ v0)
{
    const int arr = blockIdx.y;
    const float* __restrict__ w   = arr == 0 ? kw : (arr == 1 ? qw : vw);
    const float* __restrict__ bia = arr == 0 ? kb : (arr == 1 ? qb : vb);
    float* __restrict__ out       = arr == 0 ? k0 : (arr == 1 ? q0 : v0);

    __shared__ float xs[16][68];    // [k][row], padded (68%4==0 for float4, 2-way-bank-free staging)
    __shared__ float ws[16][132];   // [k][col]

    const int t  = threadIdx.x;
    const int tx = t & 15;
    const int ty = t >> 4;
    const int row0 = blockIdx.x * 64;

    float acc[4][8];
    #pragma unroll
    for (int i = 0; i < 4; i++)
        #pragma unroll
        for (int j = 0; j < 8; j++) acc[i][j] = 0.f;

    const int kk = t & 15;
    const int rr = t >> 4;

    for (int k0i = 0; k0i < 2048; k0i += 16) {
        #pragma unroll
        for (int it = 0; it < 4; it++) {
            int r = rr + it * 16;
            xs[kk][r] = x[(size_t)(row0 + r) * 2048 + k0i + kk];
        }
        #pragma unroll
        for (int it = 0; it < 8; it++) {
            int c = rr + it * 16;
            ws[kk][c] = w[(size_t)c * 2048 + k0i + kk];
        }
        __syncthreads();
        #pragma unroll
        for (int k2 = 0; k2 < 16; k2++) {
            float4 a4  = *(const float4*)&xs[k2][ty * 4];
            float4 b4a = *(const float4*)&ws[k2][tx * 8];
            float4 b4b = *(const float4*)&ws[k2][tx * 8 + 4];
            float av[4] = {a4.x, a4.y, a4.z, a4.w};
            float bv[8] = {b4a.x, b4a.y, b4a.z, b4a.w, b4b.x, b4b.y, b4b.z, b4b.w};
            #pragma unroll
            for (int i = 0; i < 4; i++)
                #pragma unroll
                for (int j = 0; j < 8; j++)
                    acc[i][j] = fmaf(av[i], bv[j], acc[i][j]);
        }
        __syncthreads();
    }
    #pragma unroll
    for (int i = 0; i < 4; i++) {
        int row = row0 + ty * 4 + i;
        float4 o0, o1;
        o0.x = acc[i][0] + bia[tx * 8 + 0]; o0.y = acc[i][1] + bia[tx * 8 + 1];
        o0.z = acc[i][2] + bia[tx * 8 + 2]; o0.w = acc[i][3] + bia[tx * 8 + 3];
        o1.x = acc[i][4] + bia[tx * 8 + 4]; o1.y = acc[i][5] + bia[tx * 8 + 5];
        o1.z = acc[i][6] + bia[tx * 8 + 6]; o1.w = acc[i][7] + bia[tx * 8 + 7];
        *(float4*)&out[(size_t)row * 128 + tx * 8]     = o0;
        *(float4*)&out[(size_t)row * 128 + tx * 8 + 4] = o1;
    }
}

// ================= beta = sigmoid(x @ beta_w^T + beta_b) ================
__global__ __launch_bounds__(256) void beta_kernel(
    const float* __restrict__ x, const float* __restrict__ bw,
    const float* __restrict__ bb, float* __restrict__ beta)
{
    const int row = blockIdx.x;
    const float* xr = x + (size_t)row * 2048;
    float s = 0.f;
    for (int j = threadIdx.x; j < 2048; j += 256) s = fmaf(xr[j], bw[j], s);
    #pragma unroll
    for (int m = 1; m < 64; m <<= 1) s += __shfl_xor(s, m, 64);
    __shared__ float red[4];
    if ((threadIdx.x & 63) == 0) red[threadIdx.x >> 6] = s;
    __syncthreads();
    if (threadIdx.x == 0) {
        float tot = red[0] + red[1] + red[2] + red[3] + bb[0];
        beta[row] = 1.f / (1.f + expf(-tot));
    }
}

// ================= 3-tap conv along s (kw=1 column of 3x3) + bias + SiLU ================
__global__ __launch_bounds__(256) void conv_silu(
    const float* __restrict__ k0, const float* __restrict__ q0, const float* __restrict__ v0,
    const float* __restrict__ kw, const float* __restrict__ qw, const float* __restrict__ vw,
    const float* __restrict__ kb, const float* __restrict__ qb, const float* __restrict__ vb,
    float* __restrict__ kc, float* __restrict__ qc, float* __restrict__ vc)
{
    const int st  = blockIdx.x;        // 8 tiles of 256 along s
    const int og  = blockIdx.y;        // 8 groups of 16 out-channels
    const int arr = blockIdx.z >> 2;
    const int b   = blockIdx.z & 3;
    const float* __restrict__ in = (arr == 0 ? k0 : arr == 1 ? q0 : v0) + (size_t)b * DD * LL;
    const float* __restrict__ w  = arr == 0 ? kw : arr == 1 ? qw : vw;
    const float* __restrict__ bi = arr == 0 ? kb : arr == 1 ? qb : vb;
    float* __restrict__ out      = (arr == 0 ? kc : arr == 1 ? qc : vc) + (size_t)b * DD * LL;

    __shared__ float wl[16 * 128 * 3];
    __shared__ float ls[258];
    const int t = threadIdx.x;
    for (int e = t; e < 16 * 128 * 3; e += 256) {
        int oo = e / 384, rem = e % 384;
        int i = rem / 3, kh = rem % 3;
        wl[e] = w[(size_t)(((og * 16 + oo) * 128 + i) * 3 + kh) * 3 + 1];
    }
    __syncthreads();

    const int s = st * 256 + t;
    float acc[16];
    #pragma unroll
    for (int oo = 0; oo < 16; oo++) acc[oo] = 0.f;

    for (int i = 0; i < 128; i++) {
        int sl = st * 256 - 1 + t;
        ls[t] = (sl >= 0 && sl < LL) ? in[(size_t)i * LL + sl] : 0.f;
        if (t < 2) {
            int s2 = st * 256 + 255 + t;
            ls[256 + t] = (s2 < LL) ? in[(size_t)i * LL + s2] : 0.f;
        }
        __syncthreads();
        float xm = ls[t], x0 = ls[t + 1], xp = ls[t + 2];
        #pragma unroll
        for (int oo = 0; oo < 16; oo++) {
            const float* wp = &wl[(oo * 128 + i) * 3];
            acc[oo] = fmaf(wp[0], xm, acc[oo]);
            acc[oo] = fmaf(wp[1], x0, acc[oo]);
            acc[oo] = fmaf(wp[2], xp, acc[oo]);
        }
        __syncthreads();
    }
    #pragma unroll
    for (int oo = 0; oo < 16; oo++) {
        int o = og * 16 + oo;
        float v = acc[oo] + bi[o];
        out[(size_t)o * LL + s] = v / (1.f + expf(-v));   // silu
    }
}

// ================= 1/max(||row||_2, 1e-12) over s for k,q ================
__global__ __launch_bounds__(256) void l2norm_reduce(
    const float* __restrict__ kc, const float* __restrict__ qc, float* __restrict__ invn)
{
    const int row = blockIdx.x;   // 0..511 = b*128+d
    const int arr = blockIdx.y;   // 0: k, 1: q
    const float* src = (arr ? qc : kc) + (size_t)row * LL;
    float s = 0.f;
    for (int j = threadIdx.x; j < LL; j += 256) { float v = src[j]; s = fmaf(v, v, s); }
    #pragma unroll
    for (int m = 1; m < 64; m <<= 1) s += __shfl_xor(s, m, 64);
    __shared__ float red[4];
    if ((threadIdx.x & 63) == 0) red[threadIdx.x >> 6] = s;
    __syncthreads();
    if (threadIdx.x == 0) {
        float n = sqrtf(red[0] + red[1] + red[2] + red[3]);
        invn[arr * 512 + row] = 1.f / fmaxf(n, 1e-12f);
    }
}

// ================= transpose (B,D,L)->(B,L,D), scaling k,q by invn ================
__global__ __launch_bounds__(256) void pack_transpose(
    const float* __restrict__ kc, const float* __restrict__ qc, const float* __restrict__ vc,
    const float* __restrict__ invn,
    float* __restrict__ kT, float* __restrict__ qT, float* __restrict__ vT)
{
    const int arr = blockIdx.z >> 2;
    const int b   = blockIdx.z & 3;
    const float* src = (arr == 0 ? kc : arr == 1 ? qc : vc) + (size_t)b * DD * LL;
    float* dst       = (arr == 0 ? kT : arr == 1 ? qT : vT) + (size_t)b * LL * DD;
    __shared__ float tile[32][33];
    const int s0 = blockIdx.x * 32, d0 = blockIdx.y * 32;
    const int c = threadIdx.x & 31, r = threadIdx.x >> 5;  // r: 0..7
    #pragma unroll
    for (int p = 0; p < 4; p++) {
        int d = d0 + r + p * 8;
        tile[r + p * 8][c] = src[(size_t)d * LL + s0 + c];
    }
    __syncthreads();
    #pragma unroll
    for (int p = 0; p < 4; p++) {
        int s = s0 + r + p * 8;
        int d = d0 + c;
        float sc = (arr < 2) ? invn[arr * 512 + b * 128 + d] : 1.f;
        dst[(size_t)s * DD + d] = tile[c][r + p * 8] * sc;
    }
}

// ================= sequential delta rule scan ================
struct StepBuf { float4 k[4]; float4 q[4]; float v; float b; };

__device__ __forceinline__ void load_step(
    const float* __restrict__ kb, const float* __restrict__ qb,
    const float* __restrict__ vb, const float* __restrict__ bbeta,
    int tt, int j0, int i, StepBuf& s)
{
    const float4* kp = (const float4*)(kb + (size_t)tt * DD + j0);
    const float4* qp = (const float4*)(qb + (size_t)tt * DD + j0);
    s.k[0] = kp[0]; s.k[1] = kp[1]; s.k[2] = kp[2]; s.k[3] = kp[3];
    s.q[0] = qp[0]; s.q[1] = qp[1]; s.q[2] = qp[2]; s.q[3] = qp[3];
    s.v = vb[(size_t)tt * DD + i];
    s.b = bbeta[tt];
}

__device__ __forceinline__ void compute_step(
    float* S, const StepBuf& sb, int part, int i, float* __restrict__ ob, int tt)
{
    const float* kk = (const float*)sb.k;
    const float* qq = (const float*)sb.q;
    // Sk partial: 4 independent chains for ILP
    float a0 = 0.f, a1 = 0.f, a2 = 0.f, a3 = 0.f;
    #pragma unroll
    for (int u = 0; u < 4; u++) {
        a0 = fmaf(S[u],      kk[u],      a0);
        a1 = fmaf(S[4 + u],  kk[4 + u],  a1);
        a2 = fmaf(S[8 + u],  kk[8 + u],  a2);
        a3 = fmaf(S[12 + u], kk[12 + u], a3);
    }
    float sk = (a0 + a1) + (a2 + a3);
    sk += __shfl_xor(sk, 1, 8);
    sk += __shfl_xor(sk, 2, 8);
    sk += __shfl_xor(sk, 4, 8);
    float coef = sb.b * (sb.v - sk);
    float o0 = 0.f, o1 = 0.f, o2 = 0.f, o3 = 0.f;
    #pragma unroll
    for (int u = 0; u < 4; u++) {
        S[u]      = fmaf(coef, kk[u],      S[u]);      o0 = fmaf(S[u],      qq[u],      o0);
        S[4 + u]  = fmaf(coef, kk[4 + u],  S[4 + u]);  o1 = fmaf(S[4 + u],  qq[4 + u],  o1);
        S[8 + u]  = fmaf(coef, kk[8 + u],  S[8 + u]);  o2 = fmaf(S[8 + u],  qq[8 + u],  o2);
        S[12 + u] = fmaf(coef, kk[12 + u], S[12 + u]); o3 = fmaf(S[12 + u], qq[12 + u], o3);
    }
    float o = (o0 + o1) + (o2 + o3);
    o += __shfl_xor(o, 1, 8);
    o += __shfl_xor(o, 2, 8);
    o += __shfl_xor(o, 4, 8);
    if (part == 0) ob[(size_t)tt * DD + i] = o;
}

__global__ __launch_bounds__(64) void delta_scan(
    const float* __restrict__ kT, const float* __restrict__ qT,
    const float* __restrict__ vT, const float* __restrict__ beta,
    float* __restrict__ dl)
{
    const int b  = blockIdx.y;
    const int ig = blockIdx.x;          // 16 groups of 8 rows
    const int t = threadIdx.x;
    const int part = t & 7;             // 8 lanes per row
    const int i = ig * 8 + (t >> 3);    // state row (v-dim)
    const int j0 = part * 16;           // 16 state cols per lane

    const float* kb = kT + (size_t)b * LL * DD;
    const float* qb = qT + (size_t)b * LL * DD;
    const float* vb = vT + (size_t)b * LL * DD;
    const float* bbeta = beta + (size_t)b * LL;
    float* ob = dl + (size_t)b * LL * DD;

    float S[16];
    #pragma unroll
    for (int u = 0; u < 16; u++) S[u] = 0.f;

    StepBuf s0_, s1_;
    load_step(kb, qb, vb, bbeta, 0, j0, i, s0_);
    for (int tt = 0; tt < LL; tt += 2) {
        load_step(kb, qb, vb, bbeta, tt + 1, j0, i, s1_);
        compute_step(S, s0_, part, i, ob, tt);
        int tn = (tt + 2 < LL) ? tt + 2 : LL - 1;
        load_step(kb, qb, vb, bbeta, tn, j0, i, s0_);
        compute_step(S, s1_, part, i, ob, tt + 1);
    }
}

// ================= RMSNorm over D ================
__global__ __launch_bounds__(128) void rms_norm(
    const float* __restrict__ dl, const float* __restrict__ rms_w, float* __restrict__ normed)
{
    const int row = blockIdx.x;
    const int t = threadIdx.x;
    float v = dl[(size_t)row * DD + t];
    float s = v * v;
    #pragma unroll
    for (int m = 1; m < 64; m <<= 1) s += __shfl_xor(s, m, 64);
    __shared__ float r2[2];
    if ((t & 63) == 0) r2[t >> 6] = s;
    __syncthreads();
    float ms = (r2[0] + r2[1]) * (1.f / 128.f);
    normed[(size_t)row * DD + t] = v * rsqrtf(ms + 1.1920928955078125e-07f) * rms_w[t];
}

// ================= out GEMM: out(8192x2048) = normed(8192x128) @ out_w^T + out_b ================
__global__ __launch_bounds__(256) void out_gemm(
    const float* __restrict__ A, const float* __restrict__ w,
    const float* __restrict__ bias, float* __restrict__ out)
{
    __shared__ float xs[16][68];
    __shared__ float ws[16][132];
    const int t  = threadIdx.x;
    const int tx = t & 15;
    const int ty = t >> 4;
    const int row0 = blockIdx.x * 64;
    const int col0 = blockIdx.y * 128;

    float acc[4][8];
    #pragma unroll
    for (int i = 0; i < 4; i++)
        #pragma unroll
        for (int j = 0; j < 8; j++) acc[i][j] = 0.f;

    const int kk = t & 15;
    const int rr = t >> 4;

    for (int k0i = 0; k0i < 128; k0i += 16) {
        #pragma unroll
        for (int it = 0; it < 4; it++) {
            int r = rr + it * 16;
            xs[kk][r] = A[(size_t)(row0 + r) * 128 + k0i + kk];
        }
        #pragma unroll
        for (int it = 0; it < 8; it++) {
            int c = rr + it * 16;
            ws[kk][c] = w[(size_t)(col0 + c) * 128 + k0i + kk];
        }
        __syncthreads();
        #pragma unroll
        for (int k2 = 0; k2 < 16; k2++) {
            float4 a4  = *(const float4*)&xs[k2][ty * 4];
            float4 b4a = *(const float4*)&ws[k2][tx * 8];
            float4 b4b = *(const float4*)&ws[k2][tx * 8 + 4];
            float av[4] = {a4.x, a4.y, a4.z, a4.w};
            float bv[8] = {b4a.x, b4a.y, b4a.z, b4a.w, b4b.x, b4b.y, b4b.z, b4b.w};
            #pragma unroll
            for (int i = 0; i < 4; i++)
                #pragma unroll
                for (int j = 0; j < 8; j++)
                    acc[i][j] = fmaf(av[i], bv[j], acc[i][j]);
        }
        __syncthreads();
    }
    #pragma unroll
    for (int i = 0; i < 4; i++) {
        int row = row0 + ty * 4 + i;
        float4 o0, o1;
        o0.x = acc[i][0] + bias[col0 + tx * 8 + 0]; o0.y = acc[i][1] + bias[col0 + tx * 8 + 1];
        o0.z = acc[i][2] + bias[col0 + tx * 8 + 2]; o0.w = acc[i][3] + bias[col0 + tx * 8 + 3];
        o1.x = acc[i][4] + bias[col0 + tx * 8 + 4]; o1.y = acc[i][5] + bias[col0 + tx * 8 + 5];
        o1.z = acc[i][6] + bias[col0 + tx * 8 + 6]; o1.w = acc[i][7] + bias[col0 + tx * 8 + 7];
        *(float4*)&out[(size_t)row * 2048 + col0 + tx * 8]     = o0;
        *(float4*)&out[(size_t)row * 2048 + col0 + tx * 8 + 4] = o1;
    }
}

extern "C" void kernel_launch(void* const* d_in, const int* in_sizes, int n_in,
                              void* d_out, int out_size, void* d_ws, size_t ws_size,
                              hipStream_t stream) {
    const float* x    = (const float*)d_in[0];
    const float* kpw  = (const float*)d_in[1];
    const float* kpb  = (const float*)d_in[2];
    const float* qpw  = (const float*)d_in[3];
    const float* qpb  = (const float*)d_in[4];
    const float* vpw  = (const float*)d_in[5];
    const float* vpb  = (const float*)d_in[6];
    const float* kcw  = (const float*)d_in[7];
    const float* kcb  = (const float*)d_in[8];
    const float* qcw  = (const float*)d_in[9];
    const float* qcb  = (const float*)d_in[10];
    const float* vcw  = (const float*)d_in[11];
    const float* vcb  = (const float*)d_in[12];
    const float* bw   = (const float*)d_in[13];
    const float* bb   = (const float*)d_in[14];
    const float* rw   = (const float*)d_in[15];
    const float* ow   = (const float*)d_in[16];
    const float* obi  = (const float*)d_in[17];
    float* out = (float*)d_out;

    float* ws = (float*)d_ws;
    const size_t NB1 = (size_t)BB * DD * LL;   // 1,048,576 floats
    float* k0   = ws;                // proj out, later reused as kT
    float* q0   = ws + NB1;
    float* v0   = ws + 2 * NB1;
    float* kc   = ws + 3 * NB1;      // conv+silu out
    float* qc   = ws + 4 * NB1;
    float* vc   = ws + 5 * NB1;
    float* dl   = ws + 6 * NB1;      // delta-rule out (B,L,D)
    float* nm   = ws + 7 * NB1;      // rmsnorm out
    float* beta = ws + 8 * NB1;      // B*L
    float* invn = beta + (size_t)BB * LL;  // 2*512

    proj_gemm<<<dim3(128, 3), 256, 0, stream>>>(x, kpw, qpw, vpw, kpb, qpb, vpb, k0, q0, v0);
    beta_kernel<<<dim3(BB * LL), 256, 0, stream>>>(x, bw, bb, beta);
    conv_silu<<<dim3(8, 8, 12), 256, 0, stream>>>(k0, q0, v0, kcw, qcw, vcw, kcb, qcb, vcb, kc, qc, vc);
    l2norm_reduce<<<dim3(512, 2), 256, 0, stream>>>(kc, qc, invn);
    pack_transpose<<<dim3(64, 4, 12), 256, 0, stream>>>(kc, qc, vc, invn, k0, q0, v0);
    delta_scan<<<dim3(16, BB), 64, 0, stream>>>(k0, q0, v0, beta, dl);
    rms_norm<<<dim3(BB * LL), 128, 0, stream>>>(dl, rw, nm);
    out_gemm<<<dim3(128, 16), 256, 0, stream>>>(nm, ow, obi, out);
}

// Round 2
// 1068.436 us; speedup vs baseline: 1.5031x; 1.5031x over previous
//
#include <hip/hip_runtime.h>
#include <math.h>

#define LL 2048
#define DD 128
#define BB 4

// ================= proj GEMM: C(8192x128 per arr) = x(8192x2048) @ w^T ================
__global__ __launch_bounds__(256) void proj_gemm(
    const float* __restrict__ x,
    const float* __restrict__ kw, const float* __restrict__ qw, const float* __restrict__ vw,
    const float* __restrict__ kb, const float* __restrict__ qb, const float* __restrict__ vb,
    float* __restrict__ k0, float* __restrict__ q0, float* __restrict__ v0)
{
    const int arr = blockIdx.y;
    const float* __restrict__ w   = arr == 0 ? kw : (arr == 1 ? qw : vw);
    const float* __restrict__ bia = arr == 0 ? kb : (arr == 1 ? qb : vb);
    float* __restrict__ out       = arr == 0 ? k0 : (arr == 1 ? q0 : v0);

    __shared__ float xs[16][68];
    __shared__ float ws[16][132];

    const int t  = threadIdx.x;
    const int tx = t & 15;
    const int ty = t >> 4;
    const int row0 = blockIdx.x * 64;

    float acc[4][8];
    #pragma unroll
    for (int i = 0; i < 4; i++)
        #pragma unroll
        for (int j = 0; j < 8; j++) acc[i][j] = 0.f;

    const int kk = t & 15;
    const int rr = t >> 4;

    for (int k0i = 0; k0i < 2048; k0i += 16) {
        #pragma unroll
        for (int it = 0; it < 4; it++) {
            int r = rr + it * 16;
            xs[kk][r] = x[(size_t)(row0 + r) * 2048 + k0i + kk];
        }
        #pragma unroll
        for (int it = 0; it < 8; it++) {
            int c = rr + it * 16;
            ws[kk][c] = w[(size_t)c * 2048 + k0i + kk];
        }
        __syncthreads();
        #pragma unroll
        for (int k2 = 0; k2 < 16; k2++) {
            float4 a4  = *(const float4*)&xs[k2][ty * 4];
            float4 b4a = *(const float4*)&ws[k2][tx * 8];
            float4 b4b = *(const float4*)&ws[k2][tx * 8 + 4];
            float av[4] = {a4.x, a4.y, a4.z, a4.w};
            float bv[8] = {b4a.x, b4a.y, b4a.z, b4a.w, b4b.x, b4b.y, b4b.z, b4b.w};
            #pragma unroll
            for (int i = 0; i < 4; i++)
                #pragma unroll
                for (int j = 0; j < 8; j++)
                    acc[i][j] = fmaf(av[i], bv[j], acc[i][j]);
        }
        __syncthreads();
    }
    #pragma unroll
    for (int i = 0; i < 4; i++) {
        int row = row0 + ty * 4 + i;
        float4 o0, o1;
        o0.x = acc[i][0] + bia[tx * 8 + 0]; o0.y = acc[i][1] + bia[tx * 8 + 1];
        o0.z = acc[i][2] + bia[tx * 8 + 2]; o0.w = acc[i][3] + bia[tx * 8 + 3];
        o1.x = acc[i][4] + bia[tx * 8 + 4]; o1.y = acc[i][5] + bia[tx * 8 + 5];
        o1.z = acc[i][6] + bia[tx * 8 + 6]; o1.w = acc[i][7] + bia[tx * 8 + 7];
        *(float4*)&out[(size_t)row * 128 + tx * 8]     = o0;
        *(float4*)&out[(size_t)row * 128 + tx * 8 + 4] = o1;
    }
}

// ================= beta = sigmoid(x @ beta_w^T + beta_b) ================
__global__ __launch_bounds__(256) void beta_kernel(
    const float* __restrict__ x, const float* __restrict__ bw,
    const float* __restrict__ bb, float* __restrict__ beta)
{
    const int row = blockIdx.x;
    const float* xr = x + (size_t)row * 2048;
    float s = 0.f;
    for (int j = threadIdx.x; j < 2048; j += 256) s = fmaf(xr[j], bw[j], s);
    #pragma unroll
    for (int m = 1; m < 64; m <<= 1) s += __shfl_xor(s, m, 64);
    __shared__ float red[4];
    if ((threadIdx.x & 63) == 0) red[threadIdx.x >> 6] = s;
    __syncthreads();
    if (threadIdx.x == 0) {
        float tot = red[0] + red[1] + red[2] + red[3] + bb[0];
        beta[row] = 1.f / (1.f + expf(-tot));
    }
}

// ================= 3-tap conv along s (kw=1 column of 3x3) + bias + SiLU ================
__global__ __launch_bounds__(256) void conv_silu(
    const float* __restrict__ k0, const float* __restrict__ q0, const float* __restrict__ v0,
    const float* __restrict__ kw, const float* __restrict__ qw, const float* __restrict__ vw,
    const float* __restrict__ kb, const float* __restrict__ qb, const float* __restrict__ vb,
    float* __restrict__ kc, float* __restrict__ qc, float* __restrict__ vc)
{
    const int st  = blockIdx.x;
    const int og  = blockIdx.y;
    const int arr = blockIdx.z >> 2;
    const int b   = blockIdx.z & 3;
    const float* __restrict__ in = (arr == 0 ? k0 : arr == 1 ? q0 : v0) + (size_t)b * DD * LL;
    const float* __restrict__ w  = arr == 0 ? kw : arr == 1 ? qw : vw;
    const float* __restrict__ bi = arr == 0 ? kb : arr == 1 ? qb : vb;
    float* __restrict__ out      = (arr == 0 ? kc : arr == 1 ? qc : vc) + (size_t)b * DD * LL;

    __shared__ float wl[16 * 128 * 3];
    __shared__ float ls[258];
    const int t = threadIdx.x;
    for (int e = t; e < 16 * 128 * 3; e += 256) {
        int oo = e / 384, rem = e % 384;
        int i = rem / 3, kh = rem % 3;
        wl[e] = w[(size_t)(((og * 16 + oo) * 128 + i) * 3 + kh) * 3 + 1];
    }
    __syncthreads();

    const int s = st * 256 + t;
    float acc[16];
    #pragma unroll
    for (int oo = 0; oo < 16; oo++) acc[oo] = 0.f;

    for (int i = 0; i < 128; i++) {
        int sl = st * 256 - 1 + t;
        ls[t] = (sl >= 0 && sl < LL) ? in[(size_t)i * LL + sl] : 0.f;
        if (t < 2) {
            int s2 = st * 256 + 255 + t;
            ls[256 + t] = (s2 < LL) ? in[(size_t)i * LL + s2] : 0.f;
        }
        __syncthreads();
        float xm = ls[t], x0 = ls[t + 1], xp = ls[t + 2];
        #pragma unroll
        for (int oo = 0; oo < 16; oo++) {
            const float* wp = &wl[(oo * 128 + i) * 3];
            acc[oo] = fmaf(wp[0], xm, acc[oo]);
            acc[oo] = fmaf(wp[1], x0, acc[oo]);
            acc[oo] = fmaf(wp[2], xp, acc[oo]);
        }
        __syncthreads();
    }
    #pragma unroll
    for (int oo = 0; oo < 16; oo++) {
        int o = og * 16 + oo;
        float v = acc[oo] + bi[o];
        out[(size_t)o * LL + s] = v / (1.f + expf(-v));
    }
}

// ================= 1/max(||row||_2, 1e-12) over s for k,q ================
__global__ __launch_bounds__(256) void l2norm_reduce(
    const float* __restrict__ kc, const float* __restrict__ qc, float* __restrict__ invn)
{
    const int row = blockIdx.x;
    const int arr = blockIdx.y;
    const float* src = (arr ? qc : kc) + (size_t)row * LL;
    float s = 0.f;
    for (int j = threadIdx.x; j < LL; j += 256) { float v = src[j]; s = fmaf(v, v, s); }
    #pragma unroll
    for (int m = 1; m < 64; m <<= 1) s += __shfl_xor(s, m, 64);
    __shared__ float red[4];
    if ((threadIdx.x & 63) == 0) red[threadIdx.x >> 6] = s;
    __syncthreads();
    if (threadIdx.x == 0) {
        float n = sqrtf(red[0] + red[1] + red[2] + red[3]);
        invn[arr * 512 + row] = 1.f / fmaxf(n, 1e-12f);
    }
}

// ================= transpose (B,D,L)->(B,L,D), scaling k,q by invn ================
__global__ __launch_bounds__(256) void pack_transpose(
    const float* __restrict__ kc, const float* __restrict__ qc, const float* __restrict__ vc,
    const float* __restrict__ invn,
    float* __restrict__ kT, float* __restrict__ qT, float* __restrict__ vT)
{
    const int arr = blockIdx.z >> 2;
    const int b   = blockIdx.z & 3;
    const float* src = (arr == 0 ? kc : arr == 1 ? qc : vc) + (size_t)b * DD * LL;
    float* dst       = (arr == 0 ? kT : arr == 1 ? qT : vT) + (size_t)b * LL * DD;
    __shared__ float tile[32][33];
    const int s0 = blockIdx.x * 32, d0 = blockIdx.y * 32;
    const int c = threadIdx.x & 31, r = threadIdx.x >> 5;
    #pragma unroll
    for (int p = 0; p < 4; p++) {
        int d = d0 + r + p * 8;
        tile[r + p * 8][c] = src[(size_t)d * LL + s0 + c];
    }
    __syncthreads();
    #pragma unroll
    for (int p = 0; p < 4; p++) {
        int s = s0 + r + p * 8;
        int d = d0 + c;
        float sc = (arr < 2) ? invn[arr * 512 + b * 128 + d] : 1.f;
        dst[(size_t)s * DD + d] = tile[c][r + p * 8] * sc;
    }
}

// ================= sequential delta rule scan ================
// 8-lane sum via DPP (VALU-latency cross-lane; groups of 8 aligned to quads/row-halves)
__device__ __forceinline__ float dpp_add8(float x) {
    int t;
    t = __builtin_amdgcn_update_dpp(0, __float_as_int(x), 0xB1, 0xF, 0xF, true);  // quad_perm [1,0,3,2]  (xor 1)
    x += __int_as_float(t);
    t = __builtin_amdgcn_update_dpp(0, __float_as_int(x), 0x4E, 0xF, 0xF, true);  // quad_perm [2,3,0,1]  (xor 2)
    x += __int_as_float(t);
    t = __builtin_amdgcn_update_dpp(0, __float_as_int(x), 0x141, 0xF, 0xF, true); // row_half_mirror (crosses quads in 8)
    x += __int_as_float(t);
    return x;
}

struct StepBuf { float4 k[4]; float4 q[4]; float v; float b; };

__device__ __forceinline__ void load_step(
    const float* __restrict__ kb, const float* __restrict__ qb,
    const float* __restrict__ vb, const float* __restrict__ bbeta,
    int tt, int j0, int i, StepBuf& s)
{
    const float4* kp = (const float4*)(kb + (size_t)tt * DD + j0);
    const float4* qp = (const float4*)(qb + (size_t)tt * DD + j0);
    s.k[0] = kp[0]; s.k[1] = kp[1]; s.k[2] = kp[2]; s.k[3] = kp[3];
    s.q[0] = qp[0]; s.q[1] = qp[1]; s.q[2] = qp[2]; s.q[3] = qp[3];
    s.v = vb[(size_t)tt * DD + i];
    s.b = bbeta[tt];
}

__device__ __forceinline__ void compute_step(
    float* S, const StepBuf& sb, int part, int i, float* __restrict__ ob, int tt)
{
    const float* kk = (const float*)sb.k;
    const float* qq = (const float*)sb.q;
    float a0 = 0.f, a1 = 0.f, a2 = 0.f, a3 = 0.f;
    #pragma unroll
    for (int u = 0; u < 4; u++) {
        a0 = fmaf(S[u],      kk[u],      a0);
        a1 = fmaf(S[4 + u],  kk[4 + u],  a1);
        a2 = fmaf(S[8 + u],  kk[8 + u],  a2);
        a3 = fmaf(S[12 + u], kk[12 + u], a3);
    }
    float sk = dpp_add8((a0 + a1) + (a2 + a3));
    float coef = sb.b * (sb.v - sk);
    float o0 = 0.f, o1 = 0.f, o2 = 0.f, o3 = 0.f;
    #pragma unroll
    for (int u = 0; u < 4; u++) {
        S[u]      = fmaf(coef, kk[u],      S[u]);      o0 = fmaf(S[u],      qq[u],      o0);
        S[4 + u]  = fmaf(coef, kk[4 + u],  S[4 + u]);  o1 = fmaf(S[4 + u],  qq[4 + u],  o1);
        S[8 + u]  = fmaf(coef, kk[8 + u],  S[8 + u]);  o2 = fmaf(S[8 + u],  qq[8 + u],  o2);
        S[12 + u] = fmaf(coef, kk[12 + u], S[12 + u]); o3 = fmaf(S[12 + u], qq[12 + u], o3);
    }
    float o = dpp_add8((o0 + o1) + (o2 + o3));
    if (part == 0) ob[(size_t)tt * DD + i] = o;
}

#define PREF 4

__global__ __launch_bounds__(64, 1) void delta_scan(
    const float* __restrict__ kT, const float* __restrict__ qT,
    const float* __restrict__ vT, const float* __restrict__ beta,
    float* __restrict__ dl)
{
    const int b  = blockIdx.y;
    const int ig = blockIdx.x;          // 16 groups of 8 rows
    const int t = threadIdx.x;
    const int part = t & 7;             // 8 lanes per row
    const int i = ig * 8 + (t >> 3);    // state row (v-dim)
    const int j0 = part * 16;           // 16 state cols per lane

    const float* kb = kT + (size_t)b * LL * DD;
    const float* qb = qT + (size_t)b * LL * DD;
    const float* vb = vT + (size_t)b * LL * DD;
    const float* bbeta = beta + (size_t)b * LL;
    float* ob = dl + (size_t)b * LL * DD;

    float S[16];
    #pragma unroll
    for (int u = 0; u < 16; u++) S[u] = 0.f;

    StepBuf buf[PREF];
    #pragma unroll
    for (int u = 0; u < PREF; u++) load_step(kb, qb, vb, bbeta, u, j0, i, buf[u]);

    for (int tt = 0; tt < LL; tt += PREF) {
        #pragma unroll
        for (int u = 0; u < PREF; u++) {
            compute_step(S, buf[u], part, i, ob, tt + u);
            int tn = tt + u + PREF;
            if (tn >= LL) tn = LL - 1;     // harmless tail reload
            load_step(kb, qb, vb, bbeta, tn, j0, i, buf[u]);
        }
    }
}

// ================= RMSNorm over D ================
__global__ __launch_bounds__(128) void rms_norm(
    const float* __restrict__ dl, const float* __restrict__ rms_w, float* __restrict__ normed)
{
    const int row = blockIdx.x;
    const int t = threadIdx.x;
    float v = dl[(size_t)row * DD + t];
    float s = v * v;
    #pragma unroll
    for (int m = 1; m < 64; m <<= 1) s += __shfl_xor(s, m, 64);
    __shared__ float r2[2];
    if ((t & 63) == 0) r2[t >> 6] = s;
    __syncthreads();
    float ms = (r2[0] + r2[1]) * (1.f / 128.f);
    normed[(size_t)row * DD + t] = v * rsqrtf(ms + 1.1920928955078125e-07f) * rms_w[t];
}

// ================= out GEMM: out(8192x2048) = normed(8192x128) @ out_w^T + out_b ================
__global__ __launch_bounds__(256) void out_gemm(
    const float* __restrict__ A, const float* __restrict__ w,
    const float* __restrict__ bias, float* __restrict__ out)
{
    __shared__ float xs[16][68];
    __shared__ float ws[16][132];
    const int t  = threadIdx.x;
    const int tx = t & 15;
    const int ty = t >> 4;
    const int row0 = blockIdx.x * 64;
    const int col0 = blockIdx.y * 128;

    float acc[4][8];
    #pragma unroll
    for (int i = 0; i < 4; i++)
        #pragma unroll
        for (int j = 0; j < 8; j++) acc[i][j] = 0.f;

    const int kk = t & 15;
    const int rr = t >> 4;

    for (int k0i = 0; k0i < 128; k0i += 16) {
        #pragma unroll
        for (int it = 0; it < 4; it++) {
            int r = rr + it * 16;
            xs[kk][r] = A[(size_t)(row0 + r) * 128 + k0i + kk];
        }
        #pragma unroll
        for (int it = 0; it < 8; it++) {
            int c = rr + it * 16;
            ws[kk][c] = w[(size_t)(col0 + c) * 128 + k0i + kk];
        }
        __syncthreads();
        #pragma unroll
        for (int k2 = 0; k2 < 16; k2++) {
            float4 a4  = *(const float4*)&xs[k2][ty * 4];
            float4 b4a = *(const float4*)&ws[k2][tx * 8];
            float4 b4b = *(const float4*)&ws[k2][tx * 8 + 4];
            float av[4] = {a4.x, a4.y, a4.z, a4.w};
            float bv[8] = {b4a.x, b4a.y, b4a.z, b4a.w, b4b.x, b4b.y, b4b.z, b4b.w};
            #pragma unroll
            for (int i = 0; i < 4; i++)
                #pragma unroll
                for (int j = 0; j < 8; j++)
                    acc[i][j] = fmaf(av[i], bv[j], acc[i][j]);
        }
        __syncthreads();
    }
    #pragma unroll
    for (int i = 0; i < 4; i++) {
        int row = row0 + ty * 4 + i;
        float4 o0, o1;
        o0.x = acc[i][0] + bias[col0 + tx * 8 + 0]; o0.y = acc[i][1] + bias[col0 + tx * 8 + 1];
        o0.z = acc[i][2] + bias[col0 + tx * 8 + 2]; o0.w = acc[i][3] + bias[col0 + tx * 8 + 3];
        o1.x = acc[i][4] + bias[col0 + tx * 8 + 4]; o1.y = acc[i][5] + bias[col0 + tx * 8 + 5];
        o1.z = acc[i][6] + bias[col0 + tx * 8 + 6]; o1.w = acc[i][7] + bias[col0 + tx * 8 + 7];
        *(float4*)&out[(size_t)row * 2048 + col0 + tx * 8]     = o0;
        *(float4*)&out[(size_t)row * 2048 + col0 + tx * 8 + 4] = o1;
    }
}

extern "C" void kernel_launch(void* const* d_in, const int* in_sizes, int n_in,
                              void* d_out, int out_size, void* d_ws, size_t ws_size,
                              hipStream_t stream) {
    const float* x    = (const float*)d_in[0];
    const float* kpw  = (const float*)d_in[1];
    const float* kpb  = (const float*)d_in[2];
    const float* qpw  = (const float*)d_in[3];
    const float* qpb  = (const float*)d_in[4];
    const float* vpw  = (const float*)d_in[5];
    const float* vpb  = (const float*)d_in[6];
    const float* kcw  = (const float*)d_in[7];
    const float* kcb  = (const float*)d_in[8];
    const float* qcw  = (const float*)d_in[9];
    const float* qcb  = (const float*)d_in[10];
    const float* vcw  = (const float*)d_in[11];
    const float* vcb  = (const float*)d_in[12];
    const float* bw   = (const float*)d_in[13];
    const float* bb   = (const float*)d_in[14];
    const float* rw   = (const float*)d_in[15];
    const float* ow   = (const float*)d_in[16];
    const float* obi  = (const float*)d_in[17];
    float* out = (float*)d_out;

    float* ws = (float*)d_ws;
    const size_t NB1 = (size_t)BB * DD * LL;
    float* k0   = ws;
    float* q0   = ws + NB1;
    float* v0   = ws + 2 * NB1;
    float* kc   = ws + 3 * NB1;
    float* qc   = ws + 4 * NB1;
    float* vc   = ws + 5 * NB1;
    float* dl   = ws + 6 * NB1;
    float* nm   = ws + 7 * NB1;
    float* beta = ws + 8 * NB1;
    float* invn = beta + (size_t)BB * LL;

    proj_gemm<<<dim3(128, 3), 256, 0, stream>>>(x, kpw, qpw, vpw, kpb, qpb, vpb, k0, q0, v0);
    beta_kernel<<<dim3(BB * LL), 256, 0, stream>>>(x, bw, bb, beta);
    conv_silu<<<dim3(8, 8, 12), 256, 0, stream>>>(k0, q0, v0, kcw, qcw, vcw, kcb, qcb, vcb, kc, qc, vc);
    l2norm_reduce<<<dim3(512, 2), 256, 0, stream>>>(kc, qc, invn);
    pack_transpose<<<dim3(64, 4, 12), 256, 0, stream>>>(kc, qc, vc, invn, k0, q0, v0);
    delta_scan<<<dim3(16, BB), 64, 0, stream>>>(k0, q0, v0, beta, dl);
    rms_norm<<<dim3(BB * LL), 128, 0, stream>>>(dl, rw, nm);
    out_gemm<<<dim3(128, 16), 256, 0, stream>>>(nm, ow, obi, out);
}

// Round 3
// 859.127 us; speedup vs baseline: 1.8694x; 1.2436x over previous
//
#include <hip/hip_runtime.h>
#include <math.h>

#define LL 2048
#define DD 128
#define BB 4

// ================= proj GEMM: C(8192x128 per arr) = x(8192x2048) @ w^T ================
__global__ __launch_bounds__(256) void proj_gemm(
    const float* __restrict__ x,
    const float* __restrict__ kw, const float* __restrict__ qw, const float* __restrict__ vw,
    const float* __restrict__ kb, const float* __restrict__ qb, const float* __restrict__ vb,
    float* __restrict__ k0, float* __restrict__ q0, float* __restrict__ v0)
{
    const int arr = blockIdx.y;
    const float* __restrict__ w   = arr == 0 ? kw : (arr == 1 ? qw : vw);
    const float* __restrict__ bia = arr == 0 ? kb : (arr == 1 ? qb : vb);
    float* __restrict__ out       = arr == 0 ? k0 : (arr == 1 ? q0 : v0);

    __shared__ float xs[16][68];
    __shared__ float ws[16][132];

    const int t  = threadIdx.x;
    const int tx = t & 15;
    const int ty = t >> 4;
    const int row0 = blockIdx.x * 64;

    float acc[4][8];
    #pragma unroll
    for (int i = 0; i < 4; i++)
        #pragma unroll
        for (int j = 0; j < 8; j++) acc[i][j] = 0.f;

    const int kk = t & 15;
    const int rr = t >> 4;

    for (int k0i = 0; k0i < 2048; k0i += 16) {
        #pragma unroll
        for (int it = 0; it < 4; it++) {
            int r = rr + it * 16;
            xs[kk][r] = x[(size_t)(row0 + r) * 2048 + k0i + kk];
        }
        #pragma unroll
        for (int it = 0; it < 8; it++) {
            int c = rr + it * 16;
            ws[kk][c] = w[(size_t)c * 2048 + k0i + kk];
        }
        __syncthreads();
        #pragma unroll
        for (int k2 = 0; k2 < 16; k2++) {
            float4 a4  = *(const float4*)&xs[k2][ty * 4];
            float4 b4a = *(const float4*)&ws[k2][tx * 8];
            float4 b4b = *(const float4*)&ws[k2][tx * 8 + 4];
            float av[4] = {a4.x, a4.y, a4.z, a4.w};
            float bv[8] = {b4a.x, b4a.y, b4a.z, b4a.w, b4b.x, b4b.y, b4b.z, b4b.w};
            #pragma unroll
            for (int i = 0; i < 4; i++)
                #pragma unroll
                for (int j = 0; j < 8; j++)
                    acc[i][j] = fmaf(av[i], bv[j], acc[i][j]);
        }
        __syncthreads();
    }
    #pragma unroll
    for (int i = 0; i < 4; i++) {
        int row = row0 + ty * 4 + i;
        float4 o0, o1;
        o0.x = acc[i][0] + bia[tx * 8 + 0]; o0.y = acc[i][1] + bia[tx * 8 + 1];
        o0.z = acc[i][2] + bia[tx * 8 + 2]; o0.w = acc[i][3] + bia[tx * 8 + 3];
        o1.x = acc[i][4] + bia[tx * 8 + 4]; o1.y = acc[i][5] + bia[tx * 8 + 5];
        o1.z = acc[i][6] + bia[tx * 8 + 6]; o1.w = acc[i][7] + bia[tx * 8 + 7];
        *(float4*)&out[(size_t)row * 128 + tx * 8]     = o0;
        *(float4*)&out[(size_t)row * 128 + tx * 8 + 4] = o1;
    }
}

// ================= beta = sigmoid(x @ beta_w^T + beta_b) ================
__global__ __launch_bounds__(256) void beta_kernel(
    const float* __restrict__ x, const float* __restrict__ bw,
    const float* __restrict__ bb, float* __restrict__ beta)
{
    const int row = blockIdx.x;
    const float* xr = x + (size_t)row * 2048;
    float s = 0.f;
    for (int j = threadIdx.x; j < 2048; j += 256) s = fmaf(xr[j], bw[j], s);
    #pragma unroll
    for (int m = 1; m < 64; m <<= 1) s += __shfl_xor(s, m, 64);
    __shared__ float red[4];
    if ((threadIdx.x & 63) == 0) red[threadIdx.x >> 6] = s;
    __syncthreads();
    if (threadIdx.x == 0) {
        float tot = red[0] + red[1] + red[2] + red[3] + bb[0];
        beta[row] = 1.f / (1.f + expf(-tot));
    }
}

// ================= 3-tap conv along s (kw=1 column of 3x3) + bias + SiLU ================
__global__ __launch_bounds__(256) void conv_silu(
    const float* __restrict__ k0, const float* __restrict__ q0, const float* __restrict__ v0,
    const float* __restrict__ kw, const float* __restrict__ qw, const float* __restrict__ vw,
    const float* __restrict__ kb, const float* __restrict__ qb, const float* __restrict__ vb,
    float* __restrict__ kc, float* __restrict__ qc, float* __restrict__ vc)
{
    const int st  = blockIdx.x;
    const int og  = blockIdx.y;
    const int arr = blockIdx.z >> 2;
    const int b   = blockIdx.z & 3;
    const float* __restrict__ in = (arr == 0 ? k0 : arr == 1 ? q0 : v0) + (size_t)b * DD * LL;
    const float* __restrict__ w  = arr == 0 ? kw : arr == 1 ? qw : vw;
    const float* __restrict__ bi = arr == 0 ? kb : arr == 1 ? qb : vb;
    float* __restrict__ out      = (arr == 0 ? kc : arr == 1 ? qc : vc) + (size_t)b * DD * LL;

    __shared__ float wl[16 * 128 * 3];
    __shared__ float ls[258];
    const int t = threadIdx.x;
    for (int e = t; e < 16 * 128 * 3; e += 256) {
        int oo = e / 384, rem = e % 384;
        int i = rem / 3, kh = rem % 3;
        wl[e] = w[(size_t)(((og * 16 + oo) * 128 + i) * 3 + kh) * 3 + 1];
    }
    __syncthreads();

    const int s = st * 256 + t;
    float acc[16];
    #pragma unroll
    for (int oo = 0; oo < 16; oo++) acc[oo] = 0.f;

    for (int i = 0; i < 128; i++) {
        int sl = st * 256 - 1 + t;
        ls[t] = (sl >= 0 && sl < LL) ? in[(size_t)i * LL + sl] : 0.f;
        if (t < 2) {
            int s2 = st * 256 + 255 + t;
            ls[256 + t] = (s2 < LL) ? in[(size_t)i * LL + s2] : 0.f;
        }
        __syncthreads();
        float xm = ls[t], x0 = ls[t + 1], xp = ls[t + 2];
        #pragma unroll
        for (int oo = 0; oo < 16; oo++) {
            const float* wp = &wl[(oo * 128 + i) * 3];
            acc[oo] = fmaf(wp[0], xm, acc[oo]);
            acc[oo] = fmaf(wp[1], x0, acc[oo]);
            acc[oo] = fmaf(wp[2], xp, acc[oo]);
        }
        __syncthreads();
    }
    #pragma unroll
    for (int oo = 0; oo < 16; oo++) {
        int o = og * 16 + oo;
        float v = acc[oo] + bi[o];
        out[(size_t)o * LL + s] = v / (1.f + expf(-v));
    }
}

// ================= 1/max(||row||_2, 1e-12) over s for k,q ================
__global__ __launch_bounds__(256) void l2norm_reduce(
    const float* __restrict__ kc, const float* __restrict__ qc, float* __restrict__ invn)
{
    const int row = blockIdx.x;
    const int arr = blockIdx.y;
    const float* src = (arr ? qc : kc) + (size_t)row * LL;
    float s = 0.f;
    for (int j = threadIdx.x; j < LL; j += 256) { float v = src[j]; s = fmaf(v, v, s); }
    #pragma unroll
    for (int m = 1; m < 64; m <<= 1) s += __shfl_xor(s, m, 64);
    __shared__ float red[4];
    if ((threadIdx.x & 63) == 0) red[threadIdx.x >> 6] = s;
    __syncthreads();
    if (threadIdx.x == 0) {
        float n = sqrtf(red[0] + red[1] + red[2] + red[3]);
        invn[arr * 512 + row] = 1.f / fmaxf(n, 1e-12f);
    }
}

// ================= transpose (B,D,L)->(B,L,D), scaling k,q by invn ================
__global__ __launch_bounds__(256) void pack_transpose(
    const float* __restrict__ kc, const float* __restrict__ qc, const float* __restrict__ vc,
    const float* __restrict__ invn,
    float* __restrict__ kT, float* __restrict__ qT, float* __restrict__ vT)
{
    const int arr = blockIdx.z >> 2;
    const int b   = blockIdx.z & 3;
    const float* src = (arr == 0 ? kc : arr == 1 ? qc : vc) + (size_t)b * DD * LL;
    float* dst       = (arr == 0 ? kT : arr == 1 ? qT : vT) + (size_t)b * LL * DD;
    __shared__ float tile[32][33];
    const int s0 = blockIdx.x * 32, d0 = blockIdx.y * 32;
    const int c = threadIdx.x & 31, r = threadIdx.x >> 5;
    #pragma unroll
    for (int p = 0; p < 4; p++) {
        int d = d0 + r + p * 8;
        tile[r + p * 8][c] = src[(size_t)d * LL + s0 + c];
    }
    __syncthreads();
    #pragma unroll
    for (int p = 0; p < 4; p++) {
        int s = s0 + r + p * 8;
        int d = d0 + c;
        float sc = (arr < 2) ? invn[arr * 512 + b * 128 + d] : 1.f;
        dst[(size_t)s * DD + d] = tile[c][r + p * 8] * sc;
    }
}

// ================= sequential delta rule scan ================
// 16-lane sum via DPP. Stages: xor1 (quad_perm), xor2 (quad_perm),
// quad-swap within 8 (row_half_mirror: valid since lanes within quads are
// already equal), 8-group swap within 16 (row_ror:8, same argument).
__device__ __forceinline__ float dpp_add16(float x) {
    int t;
    t = __builtin_amdgcn_update_dpp(0, __float_as_int(x), 0xB1, 0xF, 0xF, true);  // quad_perm [1,0,3,2]
    x += __int_as_float(t);
    t = __builtin_amdgcn_update_dpp(0, __float_as_int(x), 0x4E, 0xF, 0xF, true);  // quad_perm [2,3,0,1]
    x += __int_as_float(t);
    t = __builtin_amdgcn_update_dpp(0, __float_as_int(x), 0x141, 0xF, 0xF, true); // row_half_mirror
    x += __int_as_float(t);
    t = __builtin_amdgcn_update_dpp(0, __float_as_int(x), 0x128, 0xF, 0xF, true); // row_ror:8
    x += __int_as_float(t);
    return x;
}

struct StepBuf { float4 k[2]; float4 q[2]; float v; float b; };  // 18 floats

__device__ __forceinline__ void load_step(
    const float* __restrict__ kb, const float* __restrict__ qb,
    const float* __restrict__ vb, const float* __restrict__ bbeta,
    int tt, int j0, int i, StepBuf& s)
{
    const float4* kp = (const float4*)(kb + (size_t)tt * DD + j0);
    const float4* qp = (const float4*)(qb + (size_t)tt * DD + j0);
    s.k[0] = kp[0]; s.k[1] = kp[1];
    s.q[0] = qp[0]; s.q[1] = qp[1];
    s.v = vb[(size_t)tt * DD + i];
    s.b = bbeta[tt];
}

__device__ __forceinline__ void compute_step(
    float* S, const StepBuf& sb, int part, int i, float* __restrict__ ob, int tt)
{
    const float* kk = (const float*)sb.k;
    const float* qq = (const float*)sb.q;
    float a0 = 0.f, a1 = 0.f;
    #pragma unroll
    for (int u = 0; u < 4; u++) {
        a0 = fmaf(S[u],     kk[u],     a0);
        a1 = fmaf(S[4 + u], kk[4 + u], a1);
    }
    float sk = dpp_add16(a0 + a1);
    float coef = sb.b * (sb.v - sk);
    float o0 = 0.f, o1 = 0.f;
    #pragma unroll
    for (int u = 0; u < 4; u++) {
        S[u]     = fmaf(coef, kk[u],     S[u]);     o0 = fmaf(S[u],     qq[u],     o0);
        S[4 + u] = fmaf(coef, kk[4 + u], S[4 + u]); o1 = fmaf(S[4 + u], qq[4 + u], o1);
    }
    float o = dpp_add16(o0 + o1);
    if (part == 0) ob[(size_t)tt * DD + i] = o;
}

#define PREF 8

// 128 blocks x 1 wave. XCD swizzle: assuming round-robin blockIdx->XCD,
// batch b occupies XCDs {2b, 2b+1} so its k/q/v stream lives in 2 L2s and
// all 32 of its blocks hit L2 instead of HBM.
__global__ __launch_bounds__(64, 1) void delta_scan(
    const float* __restrict__ kT, const float* __restrict__ qT,
    const float* __restrict__ vT, const float* __restrict__ beta,
    float* __restrict__ dl)
{
    const int blk = blockIdx.x;
    const int xcd = blk & 7;
    const int b   = xcd >> 1;
    const int ig  = ((blk >> 3) << 1) | (xcd & 1);   // 0..31, 4 rows each
    const int t = threadIdx.x;
    const int part = t & 15;            // 16 lanes per row
    const int i = ig * 4 + (t >> 4);    // state row (v-dim)
    const int j0 = part * 8;            // 8 state cols per lane

    const float* kb = kT + (size_t)b * LL * DD;
    const float* qb = qT + (size_t)b * LL * DD;
    const float* vb = vT + (size_t)b * LL * DD;
    const float* bbeta = beta + (size_t)b * LL;
    float* ob = dl + (size_t)b * LL * DD;

    float S[8];
    #pragma unroll
    for (int u = 0; u < 8; u++) S[u] = 0.f;

    StepBuf buf[PREF];
    #pragma unroll
    for (int u = 0; u < PREF; u++) load_step(kb, qb, vb, bbeta, u, j0, i, buf[u]);

    for (int tt = 0; tt < LL; tt += PREF) {
        #pragma unroll
        for (int u = 0; u < PREF; u++) {
            compute_step(S, buf[u], part, i, ob, tt + u);
            int tn = tt + u + PREF;
            if (tn >= LL) tn = LL - 1;     // harmless tail reload
            load_step(kb, qb, vb, bbeta, tn, j0, i, buf[u]);
        }
    }
}

// ================= RMSNorm over D ================
__global__ __launch_bounds__(128) void rms_norm(
    const float* __restrict__ dl, const float* __restrict__ rms_w, float* __restrict__ normed)
{
    const int row = blockIdx.x;
    const int t = threadIdx.x;
    float v = dl[(size_t)row * DD + t];
    float s = v * v;
    #pragma unroll
    for (int m = 1; m < 64; m <<= 1) s += __shfl_xor(s, m, 64);
    __shared__ float r2[2];
    if ((t & 63) == 0) r2[t >> 6] = s;
    __syncthreads();
    float ms = (r2[0] + r2[1]) * (1.f / 128.f);
    normed[(size_t)row * DD + t] = v * rsqrtf(ms + 1.1920928955078125e-07f) * rms_w[t];
}

// ================= out GEMM: out(8192x2048) = normed(8192x128) @ out_w^T + out_b ================
__global__ __launch_bounds__(256) void out_gemm(
    const float* __restrict__ A, const float* __restrict__ w,
    const float* __restrict__ bias, float* __restrict__ out)
{
    __shared__ float xs[16][68];
    __shared__ float ws[16][132];
    const int t  = threadIdx.x;
    const int tx = t & 15;
    const int ty = t >> 4;
    const int row0 = blockIdx.x * 64;
    const int col0 = blockIdx.y * 128;

    float acc[4][8];
    #pragma unroll
    for (int i = 0; i < 4; i++)
        #pragma unroll
        for (int j = 0; j < 8; j++) acc[i][j] = 0.f;

    const int kk = t & 15;
    const int rr = t >> 4;

    for (int k0i = 0; k0i < 128; k0i += 16) {
        #pragma unroll
        for (int it = 0; it < 4; it++) {
            int r = rr + it * 16;
            xs[kk][r] = A[(size_t)(row0 + r) * 128 + k0i + kk];
        }
        #pragma unroll
        for (int it = 0; it < 8; it++) {
            int c = rr + it * 16;
            ws[kk][c] = w[(size_t)(col0 + c) * 128 + k0i + kk];
        }
        __syncthreads();
        #pragma unroll
        for (int k2 = 0; k2 < 16; k2++) {
            float4 a4  = *(const float4*)&xs[k2][ty * 4];
            float4 b4a = *(const float4*)&ws[k2][tx * 8];
            float4 b4b = *(const float4*)&ws[k2][tx * 8 + 4];
            float av[4] = {a4.x, a4.y, a4.z, a4.w};
            float bv[8] = {b4a.x, b4a.y, b4a.z, b4a.w, b4b.x, b4b.y, b4b.z, b4b.w};
            #pragma unroll
            for (int i = 0; i < 4; i++)
                #pragma unroll
                for (int j = 0; j < 8; j++)
                    acc[i][j] = fmaf(av[i], bv[j], acc[i][j]);
        }
        __syncthreads();
    }
    #pragma unroll
    for (int i = 0; i < 4; i++) {
        int row = row0 + ty * 4 + i;
        float4 o0, o1;
        o0.x = acc[i][0] + bias[col0 + tx * 8 + 0]; o0.y = acc[i][1] + bias[col0 + tx * 8 + 1];
        o0.z = acc[i][2] + bias[col0 + tx * 8 + 2]; o0.w = acc[i][3] + bias[col0 + tx * 8 + 3];
        o1.x = acc[i][4] + bias[col0 + tx * 8 + 4]; o1.y = acc[i][5] + bias[col0 + tx * 8 + 5];
        o1.z = acc[i][6] + bias[col0 + tx * 8 + 6]; o1.w = acc[i][7] + bias[col0 + tx * 8 + 7];
        *(float4*)&out[(size_t)row * 2048 + col0 + tx * 8]     = o0;
        *(float4*)&out[(size_t)row * 2048 + col0 + tx * 8 + 4] = o1;
    }
}

extern "C" void kernel_launch(void* const* d_in, const int* in_sizes, int n_in,
                              void* d_out, int out_size, void* d_ws, size_t ws_size,
                              hipStream_t stream) {
    const float* x    = (const float*)d_in[0];
    const float* kpw  = (const float*)d_in[1];
    const float* kpb  = (const float*)d_in[2];
    const float* qpw  = (const float*)d_in[3];
    const float* qpb  = (const float*)d_in[4];
    const float* vpw  = (const float*)d_in[5];
    const float* vpb  = (const float*)d_in[6];
    const float* kcw  = (const float*)d_in[7];
    const float* kcb  = (const float*)d_in[8];
    const float* qcw  = (const float*)d_in[9];
    const float* qcb  = (const float*)d_in[10];
    const float* vcw  = (const float*)d_in[11];
    const float* vcb  = (const float*)d_in[12];
    const float* bw   = (const float*)d_in[13];
    const float* bb   = (const float*)d_in[14];
    const float* rw   = (const float*)d_in[15];
    const float* ow   = (const float*)d_in[16];
    const float* obi  = (const float*)d_in[17];
    float* out = (float*)d_out;

    float* ws = (float*)d_ws;
    const size_t NB1 = (size_t)BB * DD * LL;
    float* k0   = ws;
    float* q0   = ws + NB1;
    float* v0   = ws + 2 * NB1;
    float* kc   = ws + 3 * NB1;
    float* qc   = ws + 4 * NB1;
    float* vc   = ws + 5 * NB1;
    float* dl   = ws + 6 * NB1;
    float* nm   = ws + 7 * NB1;
    float* beta = ws + 8 * NB1;
    float* invn = beta + (size_t)BB * LL;

    proj_gemm<<<dim3(128, 3), 256, 0, stream>>>(x, kpw, qpw, vpw, kpb, qpb, vpb, k0, q0, v0);
    beta_kernel<<<dim3(BB * LL), 256, 0, stream>>>(x, bw, bb, beta);
    conv_silu<<<dim3(8, 8, 12), 256, 0, stream>>>(k0, q0, v0, kcw, qcw, vcw, kcb, qcb, vcb, kc, qc, vc);
    l2norm_reduce<<<dim3(512, 2), 256, 0, stream>>>(kc, qc, invn);
    pack_transpose<<<dim3(64, 4, 12), 256, 0, stream>>>(kc, qc, vc, invn, k0, q0, v0);
    delta_scan<<<dim3(128), 64, 0, stream>>>(k0, q0, v0, beta, dl);
    rms_norm<<<dim3(BB * LL), 128, 0, stream>>>(dl, rw, nm);
    out_gemm<<<dim3(128, 16), 256, 0, stream>>>(nm, ow, obi, out);
}

// Round 4
// 667.103 us; speedup vs baseline: 2.4074x; 1.2878x over previous
//
#include <hip/hip_runtime.h>
#include <math.h>

#define LL 2048
#define DD 128
#define BB 4

typedef __bf16 bf16x8 __attribute__((ext_vector_type(8)));
typedef float floatx4 __attribute__((ext_vector_type(4)));

// ================= proj GEMM (bf16 MFMA): C(8192x128 x3) = x(8192x2048) @ w^T + b =========
// A = x row-major (M=8192, K=2048). B^T = w row-major (N=128, K=2048) per array.
// 128x128 tile per block, K-block 64, 4 waves in 2x2, each wave 64x64 via 4x4 16x16x32 MFMAs.
// fp32->bf16 conversion happens during LDS staging (no extra passes/workspace).
__global__ __launch_bounds__(256) void proj_gemm_mfma(
    const float* __restrict__ x,
    const float* __restrict__ kw, const float* __restrict__ qw, const float* __restrict__ vw,
    const float* __restrict__ kb, const float* __restrict__ qb, const float* __restrict__ vb,
    float* __restrict__ k0, float* __restrict__ q0, float* __restrict__ v0)
{
    const int arr = blockIdx.y;
    const float* __restrict__ w   = arr == 0 ? kw : (arr == 1 ? qw : vw);
    const float* __restrict__ bia = arr == 0 ? kb : (arr == 1 ? qb : vb);
    float* __restrict__ out       = arr == 0 ? k0 : (arr == 1 ? q0 : v0);

    __shared__ __bf16 As[128][72];   // 72: +8 pad -> frag reads 2-way (free) bank aliasing
    __shared__ __bf16 Bs[128][72];

    const int t    = threadIdx.x;
    const int wave = t >> 6, lane = t & 63;
    const int wm   = wave & 1, wn = wave >> 1;
    const int m    = lane & 15, quad = lane >> 4;
    const int row0 = blockIdx.x * 128;

    floatx4 acc[4][4] = {};

    for (int k0i = 0; k0i < 2048; k0i += 64) {
        // stage A: 128 rows x 64 cols; 1024 chunks of 8 elems; 4 chunks/thread
        #pragma unroll
        for (int c = 0; c < 4; c++) {
            int chunk = t + c * 256;
            int r = chunk >> 3, p = chunk & 7;
            const float4* src = (const float4*)&x[(size_t)(row0 + r) * 2048 + k0i + p * 8];
            float4 f0 = src[0], f1 = src[1];
            bf16x8 v8;
            v8[0] = (__bf16)f0.x; v8[1] = (__bf16)f0.y; v8[2] = (__bf16)f0.z; v8[3] = (__bf16)f0.w;
            v8[4] = (__bf16)f1.x; v8[5] = (__bf16)f1.y; v8[6] = (__bf16)f1.z; v8[7] = (__bf16)f1.w;
            *(bf16x8*)&As[r][p * 8] = v8;
        }
        // stage B: w rows 0..127 (full N), cols k0i..k0i+63
        #pragma unroll
        for (int c = 0; c < 4; c++) {
            int chunk = t + c * 256;
            int r = chunk >> 3, p = chunk & 7;
            const float4* src = (const float4*)&w[(size_t)r * 2048 + k0i + p * 8];
            float4 f0 = src[0], f1 = src[1];
            bf16x8 v8;
            v8[0] = (__bf16)f0.x; v8[1] = (__bf16)f0.y; v8[2] = (__bf16)f0.z; v8[3] = (__bf16)f0.w;
            v8[4] = (__bf16)f1.x; v8[5] = (__bf16)f1.y; v8[6] = (__bf16)f1.z; v8[7] = (__bf16)f1.w;
            *(bf16x8*)&Bs[r][p * 8] = v8;
        }
        __syncthreads();
        #pragma unroll
        for (int ks = 0; ks < 2; ks++) {
            bf16x8 af[4], bfr[4];
            #pragma unroll
            for (int i = 0; i < 4; i++)
                af[i] = *(const bf16x8*)&As[wm * 64 + i * 16 + m][ks * 32 + quad * 8];
            #pragma unroll
            for (int j = 0; j < 4; j++)
                bfr[j] = *(const bf16x8*)&Bs[wn * 64 + j * 16 + m][ks * 32 + quad * 8];
            #pragma unroll
            for (int i = 0; i < 4; i++)
                #pragma unroll
                for (int j = 0; j < 4; j++)
                    acc[i][j] = __builtin_amdgcn_mfma_f32_16x16x32_bf16(af[i], bfr[j], acc[i][j], 0, 0, 0);
        }
        __syncthreads();
    }
    // epilogue: C/D layout col=lane&15, row=quad*4+reg  [verified m89/m91]
    #pragma unroll
    for (int i = 0; i < 4; i++) {
        int grow = row0 + wm * 64 + i * 16 + quad * 4;
        #pragma unroll
        for (int j = 0; j < 4; j++) {
            int col = wn * 64 + j * 16 + m;
            float bv = bia[col];
            #pragma unroll
            for (int r = 0; r < 4; r++)
                out[(size_t)(grow + r) * 128 + col] = acc[i][j][r] + bv;
        }
    }
}

// ================= out GEMM (bf16 MFMA): out(8192x2048) = nm(8192x128) @ ow^T + ob ========
__global__ __launch_bounds__(256) void out_gemm_mfma(
    const float* __restrict__ A, const float* __restrict__ w,
    const float* __restrict__ bias, float* __restrict__ out)
{
    __shared__ __bf16 As[128][72];
    __shared__ __bf16 Bs[128][72];

    const int t    = threadIdx.x;
    const int wave = t >> 6, lane = t & 63;
    const int wm   = wave & 1, wn = wave >> 1;
    const int m    = lane & 15, quad = lane >> 4;
    const int row0 = blockIdx.x * 128;
    const int col0 = blockIdx.y * 128;

    floatx4 acc[4][4] = {};

    for (int k0i = 0; k0i < 128; k0i += 64) {
        #pragma unroll
        for (int c = 0; c < 4; c++) {
            int chunk = t + c * 256;
            int r = chunk >> 3, p = chunk & 7;
            const float4* src = (const float4*)&A[(size_t)(row0 + r) * 128 + k0i + p * 8];
            float4 f0 = src[0], f1 = src[1];
            bf16x8 v8;
            v8[0] = (__bf16)f0.x; v8[1] = (__bf16)f0.y; v8[2] = (__bf16)f0.z; v8[3] = (__bf16)f0.w;
            v8[4] = (__bf16)f1.x; v8[5] = (__bf16)f1.y; v8[6] = (__bf16)f1.z; v8[7] = (__bf16)f1.w;
            *(bf16x8*)&As[r][p * 8] = v8;
        }
        #pragma unroll
        for (int c = 0; c < 4; c++) {
            int chunk = t + c * 256;
            int r = chunk >> 3, p = chunk & 7;
            const float4* src = (const float4*)&w[(size_t)(col0 + r) * 128 + k0i + p * 8];
            float4 f0 = src[0], f1 = src[1];
            bf16x8 v8;
            v8[0] = (__bf16)f0.x; v8[1] = (__bf16)f0.y; v8[2] = (__bf16)f0.z; v8[3] = (__bf16)f0.w;
            v8[4] = (__bf16)f1.x; v8[5] = (__bf16)f1.y; v8[6] = (__bf16)f1.z; v8[7] = (__bf16)f1.w;
            *(bf16x8*)&Bs[r][p * 8] = v8;
        }
        __syncthreads();
        #pragma unroll
        for (int ks = 0; ks < 2; ks++) {
            bf16x8 af[4], bfr[4];
            #pragma unroll
            for (int i = 0; i < 4; i++)
                af[i] = *(const bf16x8*)&As[wm * 64 + i * 16 + m][ks * 32 + quad * 8];
            #pragma unroll
            for (int j = 0; j < 4; j++)
                bfr[j] = *(const bf16x8*)&Bs[wn * 64 + j * 16 + m][ks * 32 + quad * 8];
            #pragma unroll
            for (int i = 0; i < 4; i++)
                #pragma unroll
                for (int j = 0; j < 4; j++)
                    acc[i][j] = __builtin_amdgcn_mfma_f32_16x16x32_bf16(af[i], bfr[j], acc[i][j], 0, 0, 0);
        }
        __syncthreads();
    }
    #pragma unroll
    for (int i = 0; i < 4; i++) {
        int grow = row0 + wm * 64 + i * 16 + quad * 4;
        #pragma unroll
        for (int j = 0; j < 4; j++) {
            int col = col0 + wn * 64 + j * 16 + m;
            float bv = bias[col];
            #pragma unroll
            for (int r = 0; r < 4; r++)
                out[(size_t)(grow + r) * 2048 + col] = acc[i][j][r] + bv;
        }
    }
}

// ================= beta = sigmoid(x @ beta_w^T + beta_b) ================
__global__ __launch_bounds__(256) void beta_kernel(
    const float* __restrict__ x, const float* __restrict__ bw,
    const float* __restrict__ bb, float* __restrict__ beta)
{
    const int row = blockIdx.x;
    const float* xr = x + (size_t)row * 2048;
    float s = 0.f;
    for (int j = threadIdx.x; j < 2048; j += 256) s = fmaf(xr[j], bw[j], s);
    #pragma unroll
    for (int m = 1; m < 64; m <<= 1) s += __shfl_xor(s, m, 64);
    __shared__ float red[4];
    if ((threadIdx.x & 63) == 0) red[threadIdx.x >> 6] = s;
    __syncthreads();
    if (threadIdx.x == 0) {
        float tot = red[0] + red[1] + red[2] + red[3] + bb[0];
        beta[row] = 1.f / (1.f + expf(-tot));
    }
}

// ================= 3-tap conv along s (kw=1 column of 3x3) + bias + SiLU ================
__global__ __launch_bounds__(256) void conv_silu(
    const float* __restrict__ k0, const float* __restrict__ q0, const float* __restrict__ v0,
    const float* __restrict__ kw, const float* __restrict__ qw, const float* __restrict__ vw,
    const float* __restrict__ kb, const float* __restrict__ qb, const float* __restrict__ vb,
    float* __restrict__ kc, float* __restrict__ qc, float* __restrict__ vc)
{
    const int st  = blockIdx.x;
    const int og  = blockIdx.y;
    const int arr = blockIdx.z >> 2;
    const int b   = blockIdx.z & 3;
    const float* __restrict__ in = (arr == 0 ? k0 : arr == 1 ? q0 : v0) + (size_t)b * DD * LL;
    const float* __restrict__ w  = arr == 0 ? kw : arr == 1 ? qw : vw;
    const float* __restrict__ bi = arr == 0 ? kb : arr == 1 ? qb : vb;
    float* __restrict__ out      = (arr == 0 ? kc : arr == 1 ? qc : vc) + (size_t)b * DD * LL;

    __shared__ float wl[16 * 128 * 3];
    __shared__ float ls[258];
    const int t = threadIdx.x;
    for (int e = t; e < 16 * 128 * 3; e += 256) {
        int oo = e / 384, rem = e % 384;
        int i = rem / 3, kh = rem % 3;
        wl[e] = w[(size_t)(((og * 16 + oo) * 128 + i) * 3 + kh) * 3 + 1];
    }
    __syncthreads();

    const int s = st * 256 + t;
    float acc[16];
    #pragma unroll
    for (int oo = 0; oo < 16; oo++) acc[oo] = 0.f;

    for (int i = 0; i < 128; i++) {
        int sl = st * 256 - 1 + t;
        ls[t] = (sl >= 0 && sl < LL) ? in[(size_t)i * LL + sl] : 0.f;
        if (t < 2) {
            int s2 = st * 256 + 255 + t;
            ls[256 + t] = (s2 < LL) ? in[(size_t)i * LL + s2] : 0.f;
        }
        __syncthreads();
        float xm = ls[t], x0 = ls[t + 1], xp = ls[t + 2];
        #pragma unroll
        for (int oo = 0; oo < 16; oo++) {
            const float* wp = &wl[(oo * 128 + i) * 3];
            acc[oo] = fmaf(wp[0], xm, acc[oo]);
            acc[oo] = fmaf(wp[1], x0, acc[oo]);
            acc[oo] = fmaf(wp[2], xp, acc[oo]);
        }
        __syncthreads();
    }
    #pragma unroll
    for (int oo = 0; oo < 16; oo++) {
        int o = og * 16 + oo;
        float v = acc[oo] + bi[o];
        out[(size_t)o * LL + s] = v / (1.f + expf(-v));
    }
}

// ================= 1/max(||row||_2, 1e-12) over s for k,q ================
__global__ __launch_bounds__(256) void l2norm_reduce(
    const float* __restrict__ kc, const float* __restrict__ qc, float* __restrict__ invn)
{
    const int row = blockIdx.x;
    const int arr = blockIdx.y;
    const float* src = (arr ? qc : kc) + (size_t)row * LL;
    float s = 0.f;
    for (int j = threadIdx.x; j < LL; j += 256) { float v = src[j]; s = fmaf(v, v, s); }
    #pragma unroll
    for (int m = 1; m < 64; m <<= 1) s += __shfl_xor(s, m, 64);
    __shared__ float red[4];
    if ((threadIdx.x & 63) == 0) red[threadIdx.x >> 6] = s;
    __syncthreads();
    if (threadIdx.x == 0) {
        float n = sqrtf(red[0] + red[1] + red[2] + red[3]);
        invn[arr * 512 + row] = 1.f / fmaxf(n, 1e-12f);
    }
}

// ================= transpose (B,D,L)->(B,L,D), scaling k,q by invn ================
__global__ __launch_bounds__(256) void pack_transpose(
    const float* __restrict__ kc, const float* __restrict__ qc, const float* __restrict__ vc,
    const float* __restrict__ invn,
    float* __restrict__ kT, float* __restrict__ qT, float* __restrict__ vT)
{
    const int arr = blockIdx.z >> 2;
    const int b   = blockIdx.z & 3;
    const float* src = (arr == 0 ? kc : arr == 1 ? qc : vc) + (size_t)b * DD * LL;
    float* dst       = (arr == 0 ? kT : arr == 1 ? qT : vT) + (size_t)b * LL * DD;
    __shared__ float tile[32][33];
    const int s0 = blockIdx.x * 32, d0 = blockIdx.y * 32;
    const int c = threadIdx.x & 31, r = threadIdx.x >> 5;
    #pragma unroll
    for (int p = 0; p < 4; p++) {
        int d = d0 + r + p * 8;
        tile[r + p * 8][c] = src[(size_t)d * LL + s0 + c];
    }
    __syncthreads();
    #pragma unroll
    for (int p = 0; p < 4; p++) {
        int s = s0 + r + p * 8;
        int d = d0 + c;
        float sc = (arr < 2) ? invn[arr * 512 + b * 128 + d] : 1.f;
        dst[(size_t)s * DD + d] = tile[c][r + p * 8] * sc;
    }
}

// ================= sequential delta rule scan ================
__device__ __forceinline__ float dpp_add16(float x) {
    int t;
    t = __builtin_amdgcn_update_dpp(0, __float_as_int(x), 0xB1, 0xF, 0xF, true);  // quad_perm [1,0,3,2]
    x += __int_as_float(t);
    t = __builtin_amdgcn_update_dpp(0, __float_as_int(x), 0x4E, 0xF, 0xF, true);  // quad_perm [2,3,0,1]
    x += __int_as_float(t);
    t = __builtin_amdgcn_update_dpp(0, __float_as_int(x), 0x141, 0xF, 0xF, true); // row_half_mirror
    x += __int_as_float(t);
    t = __builtin_amdgcn_update_dpp(0, __float_as_int(x), 0x128, 0xF, 0xF, true); // row_ror:8
    x += __int_as_float(t);
    return x;
}

struct StepBuf { float4 k[2]; float4 q[2]; float v; float b; };  // 18 floats

__device__ __forceinline__ void load_step(
    const float* __restrict__ kb, const float* __restrict__ qb,
    const float* __restrict__ vb, const float* __restrict__ bbeta,
    int tt, int j0, int i, StepBuf& s)
{
    const float4* kp = (const float4*)(kb + (size_t)tt * DD + j0);
    const float4* qp = (const float4*)(qb + (size_t)tt * DD + j0);
    s.k[0] = kp[0]; s.k[1] = kp[1];
    s.q[0] = qp[0]; s.q[1] = qp[1];
    s.v = vb[(size_t)tt * DD + i];
    s.b = bbeta[tt];
}

__device__ __forceinline__ void compute_step(
    float* S, const StepBuf& sb, int part, int i, float* __restrict__ ob, int tt)
{
    const float* kk = (const float*)sb.k;
    const float* qq = (const float*)sb.q;
    float a0 = 0.f, a1 = 0.f;
    #pragma unroll
    for (int u = 0; u < 4; u++) {
        a0 = fmaf(S[u],     kk[u],     a0);
        a1 = fmaf(S[4 + u], kk[4 + u], a1);
    }
    float sk = dpp_add16(a0 + a1);
    float coef = sb.b * (sb.v - sk);
    float o0 = 0.f, o1 = 0.f;
    #pragma unroll
    for (int u = 0; u < 4; u++) {
        S[u]     = fmaf(coef, kk[u],     S[u]);     o0 = fmaf(S[u],     qq[u],     o0);
        S[4 + u] = fmaf(coef, kk[4 + u], S[4 + u]); o1 = fmaf(S[4 + u], qq[4 + u], o1);
    }
    float o = dpp_add16(o0 + o1);
    if (part == 0) ob[(size_t)tt * DD + i] = o;
}

#define PREF 8

__global__ __launch_bounds__(64, 1) void delta_scan(
    const float* __restrict__ kT, const float* __restrict__ qT,
    const float* __restrict__ vT, const float* __restrict__ beta,
    float* __restrict__ dl)
{
    const int blk = blockIdx.x;
    const int xcd = blk & 7;
    const int b   = xcd >> 1;
    const int ig  = ((blk >> 3) << 1) | (xcd & 1);   // 0..31, 4 rows each
    const int t = threadIdx.x;
    const int part = t & 15;
    const int i = ig * 4 + (t >> 4);
    const int j0 = part * 8;

    const float* kb = kT + (size_t)b * LL * DD;
    const float* qb = qT + (size_t)b * LL * DD;
    const float* vb = vT + (size_t)b * LL * DD;
    const float* bbeta = beta + (size_t)b * LL;
    float* ob = dl + (size_t)b * LL * DD;

    float S[8];
    #pragma unroll
    for (int u = 0; u < 8; u++) S[u] = 0.f;

    StepBuf buf[PREF];
    #pragma unroll
    for (int u = 0; u < PREF; u++) load_step(kb, qb, vb, bbeta, u, j0, i, buf[u]);

    for (int tt = 0; tt < LL; tt += PREF) {
        #pragma unroll
        for (int u = 0; u < PREF; u++) {
            compute_step(S, buf[u], part, i, ob, tt + u);
            int tn = tt + u + PREF;
            if (tn >= LL) tn = LL - 1;
            load_step(kb, qb, vb, bbeta, tn, j0, i, buf[u]);
        }
    }
}

// ================= RMSNorm over D ================
__global__ __launch_bounds__(128) void rms_norm(
    const float* __restrict__ dl, const float* __restrict__ rms_w, float* __restrict__ normed)
{
    const int row = blockIdx.x;
    const int t = threadIdx.x;
    float v = dl[(size_t)row * DD + t];
    float s = v * v;
    #pragma unroll
    for (int m = 1; m < 64; m <<= 1) s += __shfl_xor(s, m, 64);
    __shared__ float r2[2];
    if ((t & 63) == 0) r2[t >> 6] = s;
    __syncthreads();
    float ms = (r2[0] + r2[1]) * (1.f / 128.f);
    normed[(size_t)row * DD + t] = v * rsqrtf(ms + 1.1920928955078125e-07f) * rms_w[t];
}

extern "C" void kernel_launch(void* const* d_in, const int* in_sizes, int n_in,
                              void* d_out, int out_size, void* d_ws, size_t ws_size,
                              hipStream_t stream) {
    const float* x    = (const float*)d_in[0];
    const float* kpw  = (const float*)d_in[1];
    const float* kpb  = (const float*)d_in[2];
    const float* qpw  = (const float*)d_in[3];
    const float* qpb  = (const float*)d_in[4];
    const float* vpw  = (const float*)d_in[5];
    const float* vpb  = (const float*)d_in[6];
    const float* kcw  = (const float*)d_in[7];
    const float* kcb  = (const float*)d_in[8];
    const float* qcw  = (const float*)d_in[9];
    const float* qcb  = (const float*)d_in[10];
    const float* vcw  = (const float*)d_in[11];
    const float* vcb  = (const float*)d_in[12];
    const float* bw   = (const float*)d_in[13];
    const float* bb   = (const float*)d_in[14];
    const float* rw   = (const float*)d_in[15];
    const float* ow   = (const float*)d_in[16];
    const float* obi  = (const float*)d_in[17];
    float* out = (float*)d_out;

    float* ws = (float*)d_ws;
    const size_t NB1 = (size_t)BB * DD * LL;
    float* k0   = ws;
    float* q0   = ws + NB1;
    float* v0   = ws + 2 * NB1;
    float* kc   = ws + 3 * NB1;
    float* qc   = ws + 4 * NB1;
    float* vc   = ws + 5 * NB1;
    float* dl   = ws + 6 * NB1;
    float* nm   = ws + 7 * NB1;
    float* beta = ws + 8 * NB1;
    float* invn = beta + (size_t)BB * LL;

    proj_gemm_mfma<<<dim3(64, 3), 256, 0, stream>>>(x, kpw, qpw, vpw, kpb, qpb, vpb, k0, q0, v0);
    beta_kernel<<<dim3(BB * LL), 256, 0, stream>>>(x, bw, bb, beta);
    conv_silu<<<dim3(8, 8, 12), 256, 0, stream>>>(k0, q0, v0, kcw, qcw, vcw, kcb, qcb, vcb, kc, qc, vc);
    l2norm_reduce<<<dim3(512, 2), 256, 0, stream>>>(kc, qc, invn);
    pack_transpose<<<dim3(64, 4, 12), 256, 0, stream>>>(kc, qc, vc, invn, k0, q0, v0);
    delta_scan<<<dim3(128), 64, 0, stream>>>(k0, q0, v0, beta, dl);
    rms_norm<<<dim3(BB * LL), 128, 0, stream>>>(dl, rw, nm);
    out_gemm_mfma<<<dim3(64, 16), 256, 0, stream>>>(nm, ow, obi, out);
}